// Round 6
// baseline (573.731 us; speedup 1.0000x reference)
//
#include <hip/hip_runtime.h>
#include <hip/hip_bf16.h>
#include <math.h>

#define NTOK 1024
#define DDIM 768
#define MDIM 3072
#define GN 4
#define EN 8
#define NEXP 32
#define NPAIR 8192
#define EPSW 1e-6f
#define BYSPAN 3

typedef __attribute__((ext_vector_type(4))) float f32x4;
typedef __attribute__((ext_vector_type(4))) int   i32x4;
typedef __attribute__((ext_vector_type(4))) unsigned short u16x4;
typedef __attribute__((ext_vector_type(8))) __bf16 bf16x8;

__device__ __forceinline__ unsigned short f2bf(float f) {
  unsigned u = __builtin_bit_cast(unsigned, f);
  u += 0x7FFFu + ((u >> 16) & 1u);
  return (unsigned short)(u >> 16);
}

__device__ __forceinline__ void gld_lds16(const void* g, void* l) {
  __builtin_amdgcn_global_load_lds(
      (const __attribute__((address_space(1))) void*)g,
      (__attribute__((address_space(3))) void*)l, 16, 0, 0);
}

template<int N>
__device__ __forceinline__ void wait_vmcnt() {
  asm volatile("s_waitcnt vmcnt(%0)" :: "n"(N) : "memory");
}

// ---------------------------------------------------------------------------
// Kernel 0a: zero the 1KB control region (counts/offsets/cursor).
// Kernel 0b: zero y (float4-vectorized, fully parallel).
// Replaces hipMemsetAsync: the runtime fill kernel costs ~175us flat.
// ---------------------------------------------------------------------------
__global__ void init_kernel(int* __restrict__ p) { p[threadIdx.x] = 0; }

__global__ __launch_bounds__(256) void zero_y(float* __restrict__ y) {
  ((f32x4*)y)[blockIdx.x * 256 + threadIdx.x] = (f32x4){0.f, 0.f, 0.f, 0.f};
}

// ---------------------------------------------------------------------------
// Kernel 1: gating (proven correct; off critical path).
// ---------------------------------------------------------------------------
__global__ __launch_bounds__(256) void gating_kernel(
    const float* __restrict__ x, const float* __restrict__ Wg,
    const float* __restrict__ bg, const float* __restrict__ We,
    const float* __restrict__ be, int* __restrict__ counts,
    int* __restrict__ pair_e, float* __restrict__ pair_w)
{
  __shared__ float xr[DDIM];
  __shared__ float logits[36];
  const int n = blockIdx.x;
  const int tid = threadIdx.x;
  const float* xp = x + (size_t)n * DDIM;
  for (int d = tid; d < DDIM; d += 256) xr[d] = xp[d];
  __syncthreads();

  const int w = tid >> 6, lane = tid & 63;
  for (int j = 0; j < 9; ++j) {
    const int o = w + 4 * j;  // 0..35
    float s = 0.f;
    if (o < 4) {
      for (int d = lane; d < DDIM; d += 64) s += xr[d] * Wg[d * GN + o];
    } else {
      const int g = (o - 4) >> 3, e = (o - 4) & 7;
      const float* wp = We + (size_t)g * DDIM * EN + e;
      for (int d = lane; d < DDIM; d += 64) s += xr[d] * wp[d * EN];
    }
    for (int off = 32; off; off >>= 1) s += __shfl_xor(s, off);
    if (lane == 0) logits[o] = s + ((o < 4) ? bg[o] : be[o - 4]);
  }
  __syncthreads();

  if (tid == 0) {
    float gl[4];
    for (int i = 0; i < 4; ++i) gl[i] = logits[i];
    int i0 = 0;
    for (int i = 1; i < 4; ++i) if (gl[i] > gl[i0]) i0 = i;
    int i1 = -1;
    for (int i = 0; i < 4; ++i) {
      if (i == i0) continue;
      if (i1 < 0 || gl[i] > gl[i1]) i1 = i;
    }
    const float m = gl[i0];
    const float e1 = expf(gl[i1] - m);
    const float s2 = 1.f + e1;
    float gv[2] = { 1.f / s2, e1 / s2 };
    int gi[2] = { i0, i1 };
    for (int r = 0; r < 2; ++r) if (gv[r] < EPSW) gv[r] = 0.f;

    for (int r = 0; r < 2; ++r) {
      const int g = gi[r];
      float el[8];
      for (int e = 0; e < 8; ++e) el[e] = logits[4 + g * 8 + e];
      int sel[4];
      for (int q = 0; q < 4; ++q) {
        int best = -1;
        for (int e = 0; e < 8; ++e) {
          bool used = false;
          for (int p = 0; p < q; ++p) if (sel[p] == e) used = true;
          if (used) continue;
          if (best < 0 || el[e] > el[best]) best = e;
        }
        sel[q] = best;
      }
      const float mm = el[sel[0]];
      float ex[4]; float ss = 0.f;
      for (int q = 0; q < 4; ++q) { ex[q] = expf(el[sel[q]] - mm); ss += ex[q]; }
      for (int q = 0; q < 4; ++q) {
        float ew = ex[q] / ss;
        if (ew < EPSW) ew = 0.f;
        const int gbl = g * 8 + sel[q];
        const int j = r * 4 + q;
        pair_e[n * 8 + j] = gbl;
        pair_w[n * 8 + j] = gv[r] * ew;
        atomicAdd(&counts[gbl], 1);
      }
    }
  }
}

// ---------------------------------------------------------------------------
// Kernel 2: exclusive scan of 32 counts.
// ---------------------------------------------------------------------------
__global__ void scan_kernel(const int* __restrict__ counts, int* __restrict__ offsets)
{
  if (threadIdx.x == 0) {
    int a = 0;
    for (int i = 0; i < NEXP; ++i) { offsets[i] = a; a += counts[i]; }
  }
}

// ---------------------------------------------------------------------------
// Kernel 3: scatter tokens to expert segments; gather x rows as bf16.
// ---------------------------------------------------------------------------
__global__ __launch_bounds__(256) void scatter_kernel(
    const float* __restrict__ x, const int* __restrict__ pair_e,
    const float* __restrict__ pair_w, const int* __restrict__ offsets,
    int* __restrict__ cursor, int* __restrict__ slot_tok,
    float* __restrict__ slot_w, unsigned short* __restrict__ Xg)
{
  __shared__ int slots[8];
  const int n = blockIdx.x, tid = threadIdx.x;
  if (tid < 8) {
    const int e = pair_e[n * 8 + tid];
    const int s = offsets[e] + atomicAdd(&cursor[e], 1);
    slots[tid] = s;
    slot_tok[s] = n;
    slot_w[s] = pair_w[n * 8 + tid];
  }
  __syncthreads();
  const float* xp = x + (size_t)n * DDIM;
  for (int d = tid; d < DDIM; d += 256) {
    const unsigned short h = f2bf(xp[d]);
#pragma unroll
    for (int j = 0; j < 8; ++j) Xg[(size_t)slots[j] * DDIM + d] = h;
  }
}

// ---------------------------------------------------------------------------
// Kernel 4: repack weights. in: [32][R][C] fp32 -> out: [32][C][R] bf16.
// ---------------------------------------------------------------------------
template<int R, int C>
__global__ __launch_bounds__(256) void repack_kernel(
    const float* __restrict__ W, unsigned short* __restrict__ Wt)
{
  __shared__ float tile[32][33];
  const int ge = blockIdx.z;
  const int rt = blockIdx.y, ct = blockIdx.x;
  const int tid = threadIdx.x;
  {
    const int r = tid >> 3, c4 = tid & 7;
    const f32x4 v = *(const f32x4*)(W + (size_t)ge * R * C
                                      + (size_t)(rt * 32 + r) * C + ct * 32 + c4 * 4);
#pragma unroll
    for (int j = 0; j < 4; ++j) tile[r][c4 * 4 + j] = v[j];
  }
  __syncthreads();
  {
    const int n = tid >> 3, k4 = tid & 7;
    u16x4 p;
    p.x = f2bf(tile[k4 * 4 + 0][n]);
    p.y = f2bf(tile[k4 * 4 + 1][n]);
    p.z = f2bf(tile[k4 * 4 + 2][n]);
    p.w = f2bf(tile[k4 * 4 + 3][n]);
    *(u16x4*)(Wt + (size_t)ge * R * C + (size_t)(ct * 32 + n) * R + rt * 32 + k4 * 4) = p;
  }
}

// ---------------------------------------------------------------------------
// Kernel 5: pipelined GEMM, both operands k-contiguous bf16.
// C[rows x NLD] = A_seg[rows x K] * Bt[ge][NLD x K]^T.
// BM=128, BK=32, BN in {128,64}, 4 waves, mfma 16x16x32 bf16.
// 2-deep double-buffered LDS staged via global_load_lds; counted
// s_waitcnt vmcnt(L) + RAW s_barrier -> next tile's loads stay in flight
// across the barrier (T3+T4). Chunk swizzle s(r)=(r^(r>>2))&3 -> <=2-way.
// EPI 0: H = bf16(gelu(C + b1)).  EPI 1: atomicAdd y[tok] += slot_w*(C+b2).
// ---------------------------------------------------------------------------
template<int K, int NLD, int BN, int EPI>
__global__ __launch_bounds__(256) void moe_gemm_bt(
    const unsigned short* __restrict__ A, const unsigned short* __restrict__ Bt,
    const float* __restrict__ bias, const int* __restrict__ counts,
    const int* __restrict__ offsets, const float* __restrict__ slot_w,
    const int* __restrict__ slot_tok, unsigned short* __restrict__ Hout,
    float* __restrict__ Yout)
{
  constexpr int NT = K / 32;            // K-steps
  constexpr int CA = 2;                 // A 16B-chunks per thread per tile
  constexpr int CB = (BN * 64) / 4096;  // B 16B-chunks per thread per tile
  constexpr int L = CA + CB;            // loads in flight per tile
  constexpr int ABY = 8192;             // A tile bytes (128 x 64B)
  constexpr int BBY = BN * 64;          // B tile bytes
  constexpr int STRIDE = ABY + BBY;     // one buffer
  constexpr int NF = BN / 32;           // n-fragments per wave

  const int ge = blockIdx.z;
  const int cnt = counts[ge];
  const int nb = blockIdx.y;
  const int off = offsets[ge];
  const int tid = threadIdx.x;

  __shared__ __align__(16) unsigned char lds[2 * STRIDE];

  // ---- B source pointers (by-independent), pre-swizzled chunk in 64B row
  const unsigned short* bsrcp[CB];
#pragma unroll
  for (int i = 0; i < CB; ++i) {
    const int q = tid + 256 * i;
    const int n = q >> 2, c = q & 3;
    const int s = (n ^ (n >> 2)) & 3;
    bsrcp[i] = Bt + (size_t)ge * NLD * K + (size_t)(nb * BN + n) * K + (c ^ s) * 8;
  }

  // ---- wave / fragment geometry
  const int w = tid >> 6, lane = tid & 63;
  const int wr = (w >> 1) * 64, wc = (w & 1) * (BN / 2);
  const int l15 = lane & 15, l4 = lane >> 4;
  int aoff[4], boff[NF];
#pragma unroll
  for (int mf = 0; mf < 4; ++mf) {
    const int m = wr + mf * 16 + l15;
    aoff[mf] = m * 64 + ((l4 ^ ((m ^ (m >> 2)) & 3)) * 16);
  }
#pragma unroll
  for (int nf = 0; nf < NF; ++nf) {
    const int n = wc + nf * 16 + l15;
    boff[nf] = ABY + n * 64 + ((l4 ^ ((n ^ (n >> 2)) & 3)) * 16);
  }

  for (int by = blockIdx.x; by * 128 < cnt; by += BYSPAN) {
    // ---- A source pointers for this row-block
    const unsigned short* asrcp[CA];
#pragma unroll
    for (int i = 0; i < CA; ++i) {
      const int q = tid + 256 * i;
      const int m = q >> 2, c = q & 3;
      const int s = (m ^ (m >> 2)) & 3;
      int gr = by * 128 + m; if (gr >= cnt) gr = cnt - 1;
      asrcp[i] = A + (size_t)(off + gr) * K + (c ^ s) * 8;
    }

    f32x4 acc[4][NF];
#pragma unroll
    for (int mf = 0; mf < 4; ++mf)
#pragma unroll
      for (int nf = 0; nf < NF; ++nf)
        acc[mf][nf] = (f32x4){0.f, 0.f, 0.f, 0.f};

    // ---- prologue: stage tiles 0 and 1
#pragma unroll
    for (int b = 0; b < 2; ++b) {
#pragma unroll
      for (int i = 0; i < CA; ++i)
        gld_lds16(asrcp[i] + b * 32, lds + b * STRIDE + (tid + 256 * i) * 16);
#pragma unroll
      for (int i = 0; i < CB; ++i)
        gld_lds16(bsrcp[i] + b * 32, lds + b * STRIDE + ABY + (tid + 256 * i) * 16);
    }

    for (int t = 0; t < NT; ++t) {
      unsigned char* buf = lds + (t & 1) * STRIDE;
      if (t + 1 < NT) wait_vmcnt<L>(); else wait_vmcnt<0>();
      __builtin_amdgcn_s_barrier();
      asm volatile("" ::: "memory");

      bf16x8 afr[4], bfr[NF];
#pragma unroll
      for (int mf = 0; mf < 4; ++mf)
        afr[mf] = __builtin_bit_cast(bf16x8, *(const i32x4*)(buf + aoff[mf]));
#pragma unroll
      for (int nf = 0; nf < NF; ++nf)
        bfr[nf] = __builtin_bit_cast(bf16x8, *(const i32x4*)(buf + boff[nf]));
#pragma unroll
      for (int mf = 0; mf < 4; ++mf)
#pragma unroll
        for (int nf = 0; nf < NF; ++nf)
          acc[mf][nf] = __builtin_amdgcn_mfma_f32_16x16x32_bf16(
              afr[mf], bfr[nf], acc[mf][nf], 0, 0, 0);

      asm volatile("" ::: "memory");
      __builtin_amdgcn_s_barrier();

      if (t + 2 < NT) {
#pragma unroll
        for (int i = 0; i < CA; ++i)
          gld_lds16(asrcp[i] + (t + 2) * 32, buf + (tid + 256 * i) * 16);
#pragma unroll
        for (int i = 0; i < CB; ++i)
          gld_lds16(bsrcp[i] + (t + 2) * 32, buf + ABY + (tid + 256 * i) * 16);
      }
    }

    // ---- epilogue. C/D layout: col = lane&15, row = (lane>>4)*4 + j
#pragma unroll
    for (int mf = 0; mf < 4; ++mf) {
      const int rb = by * 128 + wr + mf * 16 + l4 * 4;
      if constexpr (EPI == 0) {
#pragma unroll
        for (int nf = 0; nf < NF; ++nf) {
          const int col = nb * BN + wc + nf * 16 + l15;
          const float bv = bias[(size_t)ge * NLD + col];
#pragma unroll
          for (int j = 0; j < 4; ++j) {
            const int r = rb + j;
            if (r < cnt) {
              const float v = acc[mf][nf][j] + bv;
              const float gl = 0.5f * v * (1.f + erff(v * 0.70710678118654752f));
              Hout[(size_t)(off + r) * NLD + col] = f2bf(gl);
            }
          }
        }
      } else {
#pragma unroll
        for (int j = 0; j < 4; ++j) {
          const int r = rb + j;
          if (r < cnt) {
            const int slot = off + r;
            const float sw = slot_w[slot];
            const int tok = slot_tok[slot];
#pragma unroll
            for (int nf = 0; nf < NF; ++nf) {
              const int col = nb * BN + wc + nf * 16 + l15;
              const float v = acc[mf][nf][j] + bias[(size_t)ge * NLD + col];
              atomicAdd(&Yout[(size_t)tok * DDIM + col], sw * v);
            }
          }
        }
      }
    }
  }
}

// ---------------------------------------------------------------------------
// Workspace layout (bytes):
//   0      counts[32]      256    offsets[32]    512    cursor[32]
//   1024   pair_e[8192]    33792  pair_w[8192]
//   66560  slot_tok[8192]  99328  slot_w[8192]
//   132096 Xg[8192][768] bf16   (12.6 MB)
//   12715008 H[8192][3072] bf16 (50.3 MB)
//   63046656 Wt bf16 151MB (W1t for FC1, then W2t for FC2)
//   total 214,041,600 B (confirmed available).
// ---------------------------------------------------------------------------
extern "C" void kernel_launch(void* const* d_in, const int* in_sizes, int n_in,
                              void* d_out, int out_size, void* d_ws, size_t ws_size,
                              hipStream_t stream)
{
  const float* x  = (const float*)d_in[0];
  const float* Wg = (const float*)d_in[1];
  const float* bg = (const float*)d_in[2];
  const float* We = (const float*)d_in[3];
  const float* be = (const float*)d_in[4];
  const float* W1 = (const float*)d_in[5];
  const float* b1 = (const float*)d_in[6];
  const float* W2 = (const float*)d_in[7];
  const float* b2 = (const float*)d_in[8];
  float* y = (float*)d_out;

  char* ws = (char*)d_ws;
  int*   counts   = (int*)(ws + 0);
  int*   offsets  = (int*)(ws + 256);
  int*   cursor   = (int*)(ws + 512);
  int*   pair_e   = (int*)(ws + 1024);
  float* pair_w   = (float*)(ws + 33792);
  int*   slot_tok = (int*)(ws + 66560);
  float* slot_w   = (float*)(ws + 99328);
  unsigned short* Xg = (unsigned short*)(ws + 132096);
  unsigned short* H  = (unsigned short*)(ws + 12715008);
  unsigned short* Wt = (unsigned short*)(ws + 63046656);

  init_kernel<<<1, 256, 0, stream>>>((int*)ws);
  zero_y<<<NTOK * DDIM / 1024, 256, 0, stream>>>(y);
  gating_kernel<<<NTOK, 256, 0, stream>>>(x, Wg, bg, We, be, counts, pair_e, pair_w);
  scan_kernel<<<1, 64, 0, stream>>>(counts, offsets);
  scatter_kernel<<<NTOK, 256, 0, stream>>>(x, pair_e, pair_w, offsets, cursor,
                                           slot_tok, slot_w, Xg);

  // FC1: repack W1 [768][3072] -> [3072][768] bf16, then GEMM.
  repack_kernel<DDIM, MDIM><<<dim3(MDIM / 32, DDIM / 32, NEXP), 256, 0, stream>>>(W1, Wt);
  moe_gemm_bt<DDIM, MDIM, 128, 0><<<dim3(BYSPAN, MDIM / 128, NEXP), 256, 0, stream>>>(
      Xg, Wt, b1, counts, offsets, nullptr, nullptr, H, nullptr);
  // FC2: repack W2 [3072][768] -> [768][3072] bf16 (reuse Wt), then GEMM.
  repack_kernel<MDIM, DDIM><<<dim3(DDIM / 32, MDIM / 32, NEXP), 256, 0, stream>>>(W2, Wt);
  moe_gemm_bt<MDIM, DDIM, 64, 1><<<dim3(BYSPAN, DDIM / 64, NEXP), 256, 0, stream>>>(
      H, Wt, b2, counts, offsets, slot_w, slot_tok, nullptr, y);
}

// Round 8
// 511.563 us; speedup vs baseline: 1.1215x; 1.1215x over previous
//
#include <hip/hip_runtime.h>
#include <hip/hip_bf16.h>
#include <math.h>

#define NTOK 1024
#define DDIM 768
#define MDIM 3072
#define GN 4
#define EN 8
#define NEXP 32
#define NPAIR 8192
#define EPSW 1e-6f
#define BYSPAN 3

typedef __attribute__((ext_vector_type(4))) float f32x4;
typedef __attribute__((ext_vector_type(4))) int   i32x4;
typedef __attribute__((ext_vector_type(4))) unsigned short u16x4;
typedef __attribute__((ext_vector_type(8))) __bf16 bf16x8;

__device__ __forceinline__ unsigned short f2bf(float f) {
  unsigned u = __builtin_bit_cast(unsigned, f);
  u += 0x7FFFu + ((u >> 16) & 1u);
  return (unsigned short)(u >> 16);
}

// ---------------------------------------------------------------------------
// Init + zero-y + x->bf16.
// ---------------------------------------------------------------------------
__global__ void init_kernel(int* __restrict__ p) { p[threadIdx.x] = 0; }

__global__ __launch_bounds__(256) void zero_y(float* __restrict__ y) {
  ((f32x4*)y)[blockIdx.x * 256 + threadIdx.x] = (f32x4){0.f, 0.f, 0.f, 0.f};
}

__global__ __launch_bounds__(256) void x2bf(const float* __restrict__ x,
                                            unsigned short* __restrict__ xb) {
  const int i = (blockIdx.x * 256 + threadIdx.x) * 16;
#pragma unroll
  for (int j = 0; j < 4; ++j) {
    const f32x4 v = *(const f32x4*)(x + i + j * 4);
    u16x4 p = { f2bf(v.x), f2bf(v.y), f2bf(v.z), f2bf(v.w) };
    *(u16x4*)(xb + i + j * 4) = p;
  }
}

// ---------------------------------------------------------------------------
// Kernel 1: gating (proven correct).
// ---------------------------------------------------------------------------
__global__ __launch_bounds__(256) void gating_kernel(
    const float* __restrict__ x, const float* __restrict__ Wg,
    const float* __restrict__ bg, const float* __restrict__ We,
    const float* __restrict__ be, int* __restrict__ counts,
    int* __restrict__ pair_e, float* __restrict__ pair_w)
{
  __shared__ float xr[DDIM];
  __shared__ float logits[36];
  const int n = blockIdx.x;
  const int tid = threadIdx.x;
  const float* xp = x + (size_t)n * DDIM;
  for (int d = tid; d < DDIM; d += 256) xr[d] = xp[d];
  __syncthreads();

  const int w = tid >> 6, lane = tid & 63;
  for (int j = 0; j < 9; ++j) {
    const int o = w + 4 * j;  // 0..35
    float s = 0.f;
    if (o < 4) {
      for (int d = lane; d < DDIM; d += 64) s += xr[d] * Wg[d * GN + o];
    } else {
      const int g = (o - 4) >> 3, e = (o - 4) & 7;
      const float* wp = We + (size_t)g * DDIM * EN + e;
      for (int d = lane; d < DDIM; d += 64) s += xr[d] * wp[d * EN];
    }
    for (int off = 32; off; off >>= 1) s += __shfl_xor(s, off);
    if (lane == 0) logits[o] = s + ((o < 4) ? bg[o] : be[o - 4]);
  }
  __syncthreads();

  if (tid == 0) {
    float gl[4];
    for (int i = 0; i < 4; ++i) gl[i] = logits[i];
    int i0 = 0;
    for (int i = 1; i < 4; ++i) if (gl[i] > gl[i0]) i0 = i;
    int i1 = -1;
    for (int i = 0; i < 4; ++i) {
      if (i == i0) continue;
      if (i1 < 0 || gl[i] > gl[i1]) i1 = i;
    }
    const float m = gl[i0];
    const float e1 = expf(gl[i1] - m);
    const float s2 = 1.f + e1;
    float gv[2] = { 1.f / s2, e1 / s2 };
    int gi[2] = { i0, i1 };
    for (int r = 0; r < 2; ++r) if (gv[r] < EPSW) gv[r] = 0.f;

    for (int r = 0; r < 2; ++r) {
      const int g = gi[r];
      float el[8];
      for (int e = 0; e < 8; ++e) el[e] = logits[4 + g * 8 + e];
      int sel[4];
      for (int q = 0; q < 4; ++q) {
        int best = -1;
        for (int e = 0; e < 8; ++e) {
          bool used = false;
          for (int p = 0; p < q; ++p) if (sel[p] == e) used = true;
          if (used) continue;
          if (best < 0 || el[e] > el[best]) best = e;
        }
        sel[q] = best;
      }
      const float mm = el[sel[0]];
      float ex[4]; float ss = 0.f;
      for (int q = 0; q < 4; ++q) { ex[q] = expf(el[sel[q]] - mm); ss += ex[q]; }
      for (int q = 0; q < 4; ++q) {
        float ew = ex[q] / ss;
        if (ew < EPSW) ew = 0.f;
        const int gbl = g * 8 + sel[q];
        const int j = r * 4 + q;
        pair_e[n * 8 + j] = gbl;
        pair_w[n * 8 + j] = gv[r] * ew;
        atomicAdd(&counts[gbl], 1);
      }
    }
  }
}

// ---------------------------------------------------------------------------
// Kernel 2: exclusive scan of 32 counts.
// ---------------------------------------------------------------------------
__global__ void scan_kernel(const int* __restrict__ counts, int* __restrict__ offsets)
{
  if (threadIdx.x == 0) {
    int a = 0;
    for (int i = 0; i < NEXP; ++i) { offsets[i] = a; a += counts[i]; }
  }
}

// ---------------------------------------------------------------------------
// Kernel 3: slot bookkeeping (FC1 gathers token rows directly from xb).
// ---------------------------------------------------------------------------
__global__ __launch_bounds__(256) void scatter_kernel(
    const int* __restrict__ pair_e, const float* __restrict__ pair_w,
    const int* __restrict__ offsets, int* __restrict__ cursor,
    int* __restrict__ slot_tok, float* __restrict__ slot_w)
{
  const int idx = blockIdx.x * 256 + threadIdx.x;
  if (idx < NPAIR) {
    const int e = pair_e[idx];
    const int s = offsets[e] + atomicAdd(&cursor[e], 1);
    slot_tok[s] = idx >> 3;
    slot_w[s] = pair_w[idx];
  }
}

// ---------------------------------------------------------------------------
// Kernel 4: fused GEMM reading fp32 weights directly (no repack).
// C[rows x NLD] = A_seg[rows x K](bf16) * W[ge][K x NLD](fp32).
// BM=128, BN=128, BK=32, 4 waves, mfma 16x16x32 bf16.
// ALL staging through registers (A: 2x dwordx4; B: 16 dwords), then
// convert + swizzled ds_write. 2-deep parity-unrolled pipeline; the ONLY
// explicit waits are lgkmcnt(0)+raw s_barrier — every vmcnt wait is
// compiler-inserted from register dataflow (robust to spills; no counted
// vmcnt to corrupt). Loads for tile t+2 issue before the barrier and stay
// in flight across the whole K-step.
// GATHER=1: A rows = xb[slot_tok[slot]] (FC1).  GATHER=0: A rows = H (FC2).
// EPI 0: H = bf16(gelu(C + b1)).  EPI 1: atomicAdd y[tok] += slot_w*(C+b2).
// ---------------------------------------------------------------------------
template<int K, int NLD, int EPI, int GATHER>
__global__ __launch_bounds__(256, 2) void moe_gemm_rs(
    const unsigned short* __restrict__ Abase, const float* __restrict__ W,
    const float* __restrict__ bias, const int* __restrict__ counts,
    const int* __restrict__ offsets, const float* __restrict__ slot_w,
    const int* __restrict__ slot_tok, unsigned short* __restrict__ Hout,
    float* __restrict__ Yout)
{
  constexpr int NT = K / 32;      // K-steps: 24 (FC1) or 96 (FC2), even
  constexpr int BUFB = 16384;     // one LDS buffer: A 8KB + B 8KB

  const int ge = blockIdx.z;
  const int cnt = counts[ge];
  const int nb = blockIdx.y;
  const int off = offsets[ge];
  const int tid = threadIdx.x;

  __shared__ __align__(16) unsigned char lds[2 * BUFB];

  // ---- A staging geometry: thread covers rows am, am+64; 16B chunk ac.
  const int am = tid >> 2, ac = tid & 3;
  const int asw0 = am * 64 + ((ac ^ ((am ^ (am >> 2)) & 3)) * 16);
  const int asw1 = asw0 + 4096;  // row am+64, same swizzle bits

  // ---- B staging geometry: thread = (kq, ln); 16 dwords per K-step.
  const int kq = tid >> 5, ln = tid & 31;
  const float* bp = W + (size_t)ge * K * NLD + (size_t)(kq * 4) * NLD + nb * 128 + ln;
  int bwr[4];
#pragma unroll
  for (int ii = 0; ii < 4; ++ii) {
    const int n = ln + 32 * ii;
    const int s = (n ^ (n >> 2)) & 3;
    bwr[ii] = 8192 + n * 64 + (((kq >> 1) ^ s) * 16) + ((kq & 1) * 8);
  }

  // ---- fragment geometry
  const int w = tid >> 6, lane = tid & 63;
  const int wr = (w >> 1) * 64, wc = (w & 1) * 64;
  const int l15 = lane & 15, l4 = lane >> 4;
  int aoff[4], boff[4];
#pragma unroll
  for (int mf = 0; mf < 4; ++mf) {
    const int m = wr + mf * 16 + l15;
    aoff[mf] = m * 64 + ((l4 ^ ((m ^ (m >> 2)) & 3)) * 16);
  }
#pragma unroll
  for (int nf = 0; nf < 4; ++nf) {
    const int n = wc + nf * 16 + l15;
    boff[nf] = 8192 + n * 64 + ((l4 ^ ((n ^ (n >> 2)) & 3)) * 16);
  }

  for (int by = blockIdx.x; by * 128 < cnt; by += BYSPAN) {
    // ---- A row pointers for this row-block
    int gr0 = by * 128 + am;      if (gr0 >= cnt) gr0 = cnt - 1;
    int gr1 = by * 128 + am + 64; if (gr1 >= cnt) gr1 = cnt - 1;
    const unsigned short* ap0;
    const unsigned short* ap1;
    if (GATHER) {
      ap0 = Abase + (size_t)slot_tok[off + gr0] * K + ac * 8;
      ap1 = Abase + (size_t)slot_tok[off + gr1] * K + ac * 8;
    } else {
      ap0 = Abase + (size_t)(off + gr0) * K + ac * 8;
      ap1 = Abase + (size_t)(off + gr1) * K + ac * 8;
    }

    f32x4 acc[4][4];
#pragma unroll
    for (int mf = 0; mf < 4; ++mf)
#pragma unroll
      for (int nf = 0; nf < 4; ++nf)
        acc[mf][nf] = (f32x4){0.f, 0.f, 0.f, 0.f};

    i32x4 aA0, aA1, aB0, aB1;
    float bA[16], bB[16];

#define LOADA(T, R0, R1) { \
    R0 = *(const i32x4*)(ap0 + (T) * 32); \
    R1 = *(const i32x4*)(ap1 + (T) * 32); }
#define LOADB(T, BS) { _Pragma("unroll") \
    for (int ii = 0; ii < 4; ++ii) { _Pragma("unroll") \
      for (int jj = 0; jj < 4; ++jj) \
        BS[ii * 4 + jj] = bp[(size_t)((T) * 32 + jj) * NLD + 32 * ii]; } }
#define CVTW(R0, R1, BS, BASE) { \
    *(i32x4*)((BASE) + asw0) = R0; \
    *(i32x4*)((BASE) + asw1) = R1; \
    _Pragma("unroll") \
    for (int ii = 0; ii < 4; ++ii) { \
      u16x4 p = { f2bf(BS[ii*4+0]), f2bf(BS[ii*4+1]), f2bf(BS[ii*4+2]), f2bf(BS[ii*4+3]) }; \
      *(u16x4*)((BASE) + bwr[ii]) = p; } }
#define COMPUTE(BASE) { bf16x8 afr[4], bfr[4]; _Pragma("unroll") \
    for (int mf = 0; mf < 4; ++mf) \
      afr[mf] = __builtin_bit_cast(bf16x8, *(const i32x4*)((BASE) + aoff[mf])); \
    _Pragma("unroll") \
    for (int nf = 0; nf < 4; ++nf) \
      bfr[nf] = __builtin_bit_cast(bf16x8, *(const i32x4*)((BASE) + boff[nf])); \
    _Pragma("unroll") \
    for (int mf = 0; mf < 4; ++mf) { _Pragma("unroll") \
      for (int nf = 0; nf < 4; ++nf) \
        acc[mf][nf] = __builtin_amdgcn_mfma_f32_16x16x32_bf16( \
            afr[mf], bfr[nf], acc[mf][nf], 0, 0, 0); } }

    // ---- prologue: load tiles 0 (setA) and 1 (setB)
    LOADA(0, aA0, aA1); LOADB(0, bA);
    LOADA(1, aB0, aB1); LOADB(1, bB);

    for (int t = 0; t < NT; t += 2) {
      // ---- even step: tile t from setA -> buf0
      CVTW(aA0, aA1, bA, lds);              // compiler waits vmcnt for setA
      if (t + 2 < NT) { LOADA(t + 2, aA0, aA1); LOADB(t + 2, bA); }
      asm volatile("s_waitcnt lgkmcnt(0)" ::: "memory");
      __builtin_amdgcn_s_barrier();
      COMPUTE(lds);
      asm volatile("" ::: "memory");
      __builtin_amdgcn_s_barrier();
      // ---- odd step: tile t+1 from setB -> buf1
      CVTW(aB0, aB1, bB, lds + BUFB);
      if (t + 3 < NT) { LOADA(t + 3, aB0, aB1); LOADB(t + 3, bB); }
      asm volatile("s_waitcnt lgkmcnt(0)" ::: "memory");
      __builtin_amdgcn_s_barrier();
      COMPUTE(lds + BUFB);
      asm volatile("" ::: "memory");
      __builtin_amdgcn_s_barrier();
    }
#undef LOADA
#undef LOADB
#undef CVTW
#undef COMPUTE

    // ---- epilogue. C/D layout: col = lane&15, row = (lane>>4)*4 + j
#pragma unroll
    for (int mf = 0; mf < 4; ++mf) {
      const int rb = by * 128 + wr + mf * 16 + l4 * 4;
      if constexpr (EPI == 0) {
#pragma unroll
        for (int nf = 0; nf < 4; ++nf) {
          const int col = nb * 128 + wc + nf * 16 + l15;
          const float bv = bias[(size_t)ge * NLD + col];
#pragma unroll
          for (int j = 0; j < 4; ++j) {
            const int r = rb + j;
            if (r < cnt) {
              const float v = acc[mf][nf][j] + bv;
              const float gl = 0.5f * v * (1.f + erff(v * 0.70710678118654752f));
              Hout[(size_t)(off + r) * NLD + col] = f2bf(gl);
            }
          }
        }
      } else {
#pragma unroll
        for (int j = 0; j < 4; ++j) {
          const int r = rb + j;
          if (r < cnt) {
            const int slot = off + r;
            const float sw = slot_w[slot];
            const int tok = slot_tok[slot];
#pragma unroll
            for (int nf = 0; nf < 4; ++nf) {
              const int col = nb * 128 + wc + nf * 16 + l15;
              const float v = acc[mf][nf][j] + bias[(size_t)ge * NLD + col];
              atomicAdd(&Yout[(size_t)tok * DDIM + col], sw * v);
            }
          }
        }
      }
    }
  }
}

// ---------------------------------------------------------------------------
// Workspace layout (bytes):
//   0      counts[32]      256    offsets[32]    512   cursor[32]
//   1024   pair_e[8192]    33792  pair_w[8192]
//   66560  slot_tok[8192]  99328  slot_w[8192]
//   132096 xb[1024][768] bf16 (1.57 MB)
//   12715008 H[8192][3072] bf16 (50.3 MB)     total ~63 MB (ws ~1.2 GB)
// ---------------------------------------------------------------------------
extern "C" void kernel_launch(void* const* d_in, const int* in_sizes, int n_in,
                              void* d_out, int out_size, void* d_ws, size_t ws_size,
                              hipStream_t stream)
{
  const float* x  = (const float*)d_in[0];
  const float* Wg = (const float*)d_in[1];
  const float* bg = (const float*)d_in[2];
  const float* We = (const float*)d_in[3];
  const float* be = (const float*)d_in[4];
  const float* W1 = (const float*)d_in[5];
  const float* b1 = (const float*)d_in[6];
  const float* W2 = (const float*)d_in[7];
  const float* b2 = (const float*)d_in[8];
  float* y = (float*)d_out;

  char* ws = (char*)d_ws;
  int*   counts   = (int*)(ws + 0);
  int*   offsets  = (int*)(ws + 256);
  int*   cursor   = (int*)(ws + 512);
  int*   pair_e   = (int*)(ws + 1024);
  float* pair_w   = (float*)(ws + 33792);
  int*   slot_tok = (int*)(ws + 66560);
  float* slot_w   = (float*)(ws + 99328);
  unsigned short* xb = (unsigned short*)(ws + 132096);
  unsigned short* H  = (unsigned short*)(ws + 12715008);

  init_kernel<<<1, 256, 0, stream>>>((int*)ws);
  zero_y<<<NTOK * DDIM / 1024, 256, 0, stream>>>(y);
  x2bf<<<NTOK * DDIM / 4096, 256, 0, stream>>>(x, xb);
  gating_kernel<<<NTOK, 256, 0, stream>>>(x, Wg, bg, We, be, counts, pair_e, pair_w);
  scan_kernel<<<1, 64, 0, stream>>>(counts, offsets);
  scatter_kernel<<<NPAIR / 256, 256, 0, stream>>>(pair_e, pair_w, offsets, cursor,
                                                  slot_tok, slot_w);

  // FC1: direct from W1 fp32; A gathered from xb via slot_tok.
  moe_gemm_rs<DDIM, MDIM, 0, 1><<<dim3(BYSPAN, MDIM / 128, NEXP), 256, 0, stream>>>(
      xb, W1, b1, counts, offsets, nullptr, slot_tok, H, nullptr);
  // FC2: from H, W2 fp32 direct; fused scaled-atomic epilogue into y.
  moe_gemm_rs<MDIM, DDIM, 1, 0><<<dim3(BYSPAN, DDIM / 128, NEXP), 256, 0, stream>>>(
      H, W2, b2, counts, offsets, slot_w, slot_tok, nullptr, y);
}

// Round 9
// 493.798 us; speedup vs baseline: 1.1619x; 1.0360x over previous
//
#include <hip/hip_runtime.h>
#include <hip/hip_bf16.h>
#include <math.h>

#define NTOK 1024
#define DDIM 768
#define MDIM 3072
#define GN 4
#define EN 8
#define NEXP 32
#define NPAIR 8192
#define EPSW 1e-6f
#define BYSPAN 3

typedef __attribute__((ext_vector_type(4))) float f32x4;
typedef __attribute__((ext_vector_type(4))) int   i32x4;
typedef __attribute__((ext_vector_type(4))) unsigned short u16x4;
typedef __attribute__((ext_vector_type(8))) __bf16 bf16x8;

__device__ __forceinline__ unsigned short f2bf(float f) {
  unsigned u = __builtin_bit_cast(unsigned, f);
  u += 0x7FFFu + ((u >> 16) & 1u);
  return (unsigned short)(u >> 16);
}

// ---------------------------------------------------------------------------
// Init + zero-y + x->bf16.
// ---------------------------------------------------------------------------
__global__ void init_kernel(int* __restrict__ p) { p[threadIdx.x] = 0; }

__global__ __launch_bounds__(256) void zero_y(float* __restrict__ y) {
  ((f32x4*)y)[blockIdx.x * 256 + threadIdx.x] = (f32x4){0.f, 0.f, 0.f, 0.f};
}

__global__ __launch_bounds__(256) void x2bf(const float* __restrict__ x,
                                            unsigned short* __restrict__ xb) {
  const int i = (blockIdx.x * 256 + threadIdx.x) * 16;
#pragma unroll
  for (int j = 0; j < 4; ++j) {
    const f32x4 v = *(const f32x4*)(x + i + j * 4);
    u16x4 p = { f2bf(v.x), f2bf(v.y), f2bf(v.z), f2bf(v.w) };
    *(u16x4*)(xb + i + j * 4) = p;
  }
}

// ---------------------------------------------------------------------------
// Kernel 1: gating (proven correct).
// ---------------------------------------------------------------------------
__global__ __launch_bounds__(256) void gating_kernel(
    const float* __restrict__ x, const float* __restrict__ Wg,
    const float* __restrict__ bg, const float* __restrict__ We,
    const float* __restrict__ be, int* __restrict__ counts,
    int* __restrict__ pair_e, float* __restrict__ pair_w)
{
  __shared__ float xr[DDIM];
  __shared__ float logits[36];
  const int n = blockIdx.x;
  const int tid = threadIdx.x;
  const float* xp = x + (size_t)n * DDIM;
  for (int d = tid; d < DDIM; d += 256) xr[d] = xp[d];
  __syncthreads();

  const int w = tid >> 6, lane = tid & 63;
  for (int j = 0; j < 9; ++j) {
    const int o = w + 4 * j;  // 0..35
    float s = 0.f;
    if (o < 4) {
      for (int d = lane; d < DDIM; d += 64) s += xr[d] * Wg[d * GN + o];
    } else {
      const int g = (o - 4) >> 3, e = (o - 4) & 7;
      const float* wp = We + (size_t)g * DDIM * EN + e;
      for (int d = lane; d < DDIM; d += 64) s += xr[d] * wp[d * EN];
    }
    for (int off = 32; off; off >>= 1) s += __shfl_xor(s, off);
    if (lane == 0) logits[o] = s + ((o < 4) ? bg[o] : be[o - 4]);
  }
  __syncthreads();

  if (tid == 0) {
    float gl[4];
    for (int i = 0; i < 4; ++i) gl[i] = logits[i];
    int i0 = 0;
    for (int i = 1; i < 4; ++i) if (gl[i] > gl[i0]) i0 = i;
    int i1 = -1;
    for (int i = 0; i < 4; ++i) {
      if (i == i0) continue;
      if (i1 < 0 || gl[i] > gl[i1]) i1 = i;
    }
    const float m = gl[i0];
    const float e1 = expf(gl[i1] - m);
    const float s2 = 1.f + e1;
    float gv[2] = { 1.f / s2, e1 / s2 };
    int gi[2] = { i0, i1 };
    for (int r = 0; r < 2; ++r) if (gv[r] < EPSW) gv[r] = 0.f;

    for (int r = 0; r < 2; ++r) {
      const int g = gi[r];
      float el[8];
      for (int e = 0; e < 8; ++e) el[e] = logits[4 + g * 8 + e];
      int sel[4];
      for (int q = 0; q < 4; ++q) {
        int best = -1;
        for (int e = 0; e < 8; ++e) {
          bool used = false;
          for (int p = 0; p < q; ++p) if (sel[p] == e) used = true;
          if (used) continue;
          if (best < 0 || el[e] > el[best]) best = e;
        }
        sel[q] = best;
      }
      const float mm = el[sel[0]];
      float ex[4]; float ss = 0.f;
      for (int q = 0; q < 4; ++q) { ex[q] = expf(el[sel[q]] - mm); ss += ex[q]; }
      for (int q = 0; q < 4; ++q) {
        float ew = ex[q] / ss;
        if (ew < EPSW) ew = 0.f;
        const int gbl = g * 8 + sel[q];
        const int j = r * 4 + q;
        pair_e[n * 8 + j] = gbl;
        pair_w[n * 8 + j] = gv[r] * ew;
        atomicAdd(&counts[gbl], 1);
      }
    }
  }
}

// ---------------------------------------------------------------------------
// Kernel 2: exclusive scan of 32 counts.
// ---------------------------------------------------------------------------
__global__ void scan_kernel(const int* __restrict__ counts, int* __restrict__ offsets)
{
  if (threadIdx.x == 0) {
    int a = 0;
    for (int i = 0; i < NEXP; ++i) { offsets[i] = a; a += counts[i]; }
  }
}

// ---------------------------------------------------------------------------
// Kernel 3: slot bookkeeping (FC1 gathers token rows directly from xb).
// ---------------------------------------------------------------------------
__global__ __launch_bounds__(256) void scatter_kernel(
    const int* __restrict__ pair_e, const float* __restrict__ pair_w,
    const int* __restrict__ offsets, int* __restrict__ cursor,
    int* __restrict__ slot_tok, float* __restrict__ slot_w)
{
  const int idx = blockIdx.x * 256 + threadIdx.x;
  if (idx < NPAIR) {
    const int e = pair_e[idx];
    const int s = offsets[e] + atomicAdd(&cursor[e], 1);
    slot_tok[s] = idx >> 3;
    slot_w[s] = pair_w[idx];
  }
}

// ---------------------------------------------------------------------------
// Kernel 4: fused GEMM reading fp32 weights directly (no repack).
// C[rows x NLD] = A_seg[rows x K](bf16) * W[ge][K x NLD](fp32).
// BM=128, BN=128, BK=32, 4 waves, mfma 16x16x32 bf16.
// 3-deep REGISTER pipeline (sets A/B/C, period-6 unrolled so all reg
// indices are static): at step t, loads for tile t+2 are issued BEFORE
// the convert of tile t consumes its set — load issue is never blocked
// by the tile-t wait. ONE barrier per K-step (after stage, before
// compute; 2-step skew provably blocked). All vmcnt waits are
// compiler-inserted from register dataflow (robust; no counted vmcnt).
// GATHER=1: A rows = xb[slot_tok[slot]] (FC1).  GATHER=0: A rows = H (FC2).
// EPI 0: H = bf16(gelu(C + b1)).  EPI 1: atomicAdd y[tok] += slot_w*(C+b2).
// ---------------------------------------------------------------------------
template<int K, int NLD, int EPI, int GATHER>
__global__ __launch_bounds__(256, 2) void moe_gemm_rs(
    const unsigned short* __restrict__ Abase, const float* __restrict__ W,
    const float* __restrict__ bias, const int* __restrict__ counts,
    const int* __restrict__ offsets, const float* __restrict__ slot_w,
    const int* __restrict__ slot_tok, unsigned short* __restrict__ Hout,
    float* __restrict__ Yout)
{
  constexpr int NT = K / 32;      // K-steps: 24 (FC1) or 96 (FC2); both %6==0
  constexpr int BUFB = 16384;     // one LDS buffer: A 8KB + B 8KB

  const int ge = blockIdx.z;
  const int cnt = counts[ge];
  const int nb = blockIdx.y;
  const int off = offsets[ge];
  const int tid = threadIdx.x;

  __shared__ __align__(16) unsigned char lds[2 * BUFB];

  // ---- A staging geometry: thread covers rows am, am+64; 16B chunk ac.
  const int am = tid >> 2, ac = tid & 3;
  const int asw0 = am * 64 + ((ac ^ ((am ^ (am >> 2)) & 3)) * 16);
  const int asw1 = asw0 + 4096;  // row am+64, same swizzle bits

  // ---- B staging geometry: thread = (kq, ln); 16 dwords per K-step.
  const int kq = tid >> 5, ln = tid & 31;
  const float* bp = W + (size_t)ge * K * NLD + (size_t)(kq * 4) * NLD + nb * 128 + ln;
  int bwr[4];
#pragma unroll
  for (int ii = 0; ii < 4; ++ii) {
    const int n = ln + 32 * ii;
    const int s = (n ^ (n >> 2)) & 3;
    bwr[ii] = 8192 + n * 64 + (((kq >> 1) ^ s) * 16) + ((kq & 1) * 8);
  }

  // ---- fragment geometry
  const int w = tid >> 6, lane = tid & 63;
  const int wr = (w >> 1) * 64, wc = (w & 1) * 64;
  const int l15 = lane & 15, l4 = lane >> 4;
  int aoff[4], boff[4];
#pragma unroll
  for (int mf = 0; mf < 4; ++mf) {
    const int m = wr + mf * 16 + l15;
    aoff[mf] = m * 64 + ((l4 ^ ((m ^ (m >> 2)) & 3)) * 16);
  }
#pragma unroll
  for (int nf = 0; nf < 4; ++nf) {
    const int n = wc + nf * 16 + l15;
    boff[nf] = 8192 + n * 64 + ((l4 ^ ((n ^ (n >> 2)) & 3)) * 16);
  }

  for (int by = blockIdx.x; by * 128 < cnt; by += BYSPAN) {
    // ---- A row pointers for this row-block
    int gr0 = by * 128 + am;      if (gr0 >= cnt) gr0 = cnt - 1;
    int gr1 = by * 128 + am + 64; if (gr1 >= cnt) gr1 = cnt - 1;
    const unsigned short* ap0;
    const unsigned short* ap1;
    if (GATHER) {
      ap0 = Abase + (size_t)slot_tok[off + gr0] * K + ac * 8;
      ap1 = Abase + (size_t)slot_tok[off + gr1] * K + ac * 8;
    } else {
      ap0 = Abase + (size_t)(off + gr0) * K + ac * 8;
      ap1 = Abase + (size_t)(off + gr1) * K + ac * 8;
    }

    f32x4 acc[4][4];
#pragma unroll
    for (int mf = 0; mf < 4; ++mf)
#pragma unroll
      for (int nf = 0; nf < 4; ++nf)
        acc[mf][nf] = (f32x4){0.f, 0.f, 0.f, 0.f};

    i32x4 aA0, aA1, aB0, aB1, aC0, aC1;
    float bA[16], bB[16], bC[16];

#define LOADA(T, R0, R1) { \
    R0 = *(const i32x4*)(ap0 + (T) * 32); \
    R1 = *(const i32x4*)(ap1 + (T) * 32); }
#define LOADB(T, BS) { _Pragma("unroll") \
    for (int ii = 0; ii < 4; ++ii) { _Pragma("unroll") \
      for (int jj = 0; jj < 4; ++jj) \
        BS[ii * 4 + jj] = bp[(size_t)((T) * 32 + jj) * NLD + 32 * ii]; } }
#define CVTW(R0, R1, BS, BASE) { \
    *(i32x4*)((BASE) + asw0) = R0; \
    *(i32x4*)((BASE) + asw1) = R1; \
    _Pragma("unroll") \
    for (int ii = 0; ii < 4; ++ii) { \
      u16x4 p = { f2bf(BS[ii*4+0]), f2bf(BS[ii*4+1]), f2bf(BS[ii*4+2]), f2bf(BS[ii*4+3]) }; \
      *(u16x4*)((BASE) + bwr[ii]) = p; } }
#define COMPUTE(BASE) { bf16x8 afr[4], bfr[4]; _Pragma("unroll") \
    for (int mf = 0; mf < 4; ++mf) \
      afr[mf] = __builtin_bit_cast(bf16x8, *(const i32x4*)((BASE) + aoff[mf])); \
    _Pragma("unroll") \
    for (int nf = 0; nf < 4; ++nf) \
      bfr[nf] = __builtin_bit_cast(bf16x8, *(const i32x4*)((BASE) + boff[nf])); \
    _Pragma("unroll") \
    for (int mf = 0; mf < 4; ++mf) { _Pragma("unroll") \
      for (int nf = 0; nf < 4; ++nf) \
        acc[mf][nf] = __builtin_amdgcn_mfma_f32_16x16x32_bf16( \
            afr[mf], bfr[nf], acc[mf][nf], 0, 0, 0); } }
// One K-step: issue loads(t+2) into the set freed last step (never blocked
// by tile-t's wait), then convert+write tile t (compiler-inserted vmcnt
// wait), one barrier, compute. No post-compute barrier (skew-safe).
#define STEP(T, C0, C1, CB, I0, I1, IB, BASE) { \
    if ((T) + 2 < NT) { LOADA((T) + 2, I0, I1); LOADB((T) + 2, IB); } \
    CVTW(C0, C1, CB, BASE); \
    asm volatile("s_waitcnt lgkmcnt(0)" ::: "memory"); \
    __builtin_amdgcn_s_barrier(); \
    COMPUTE(BASE); \
  }

    // ---- prologue: load tiles 0 (set A) and 1 (set B)
    LOADA(0, aA0, aA1); LOADB(0, bA);
    LOADA(1, aB0, aB1); LOADB(1, bB);

    for (int t = 0; t < NT; t += 6) {
      STEP(t + 0, aA0, aA1, bA, aC0, aC1, bC, lds);
      STEP(t + 1, aB0, aB1, bB, aA0, aA1, bA, lds + BUFB);
      STEP(t + 2, aC0, aC1, bC, aB0, aB1, bB, lds);
      STEP(t + 3, aA0, aA1, bA, aC0, aC1, bC, lds + BUFB);
      STEP(t + 4, aB0, aB1, bB, aA0, aA1, bA, lds);
      STEP(t + 5, aC0, aC1, bC, aB0, aB1, bB, lds + BUFB);
    }
#undef LOADA
#undef LOADB
#undef CVTW
#undef COMPUTE
#undef STEP

    // ---- epilogue. C/D layout: col = lane&15, row = (lane>>4)*4 + j
#pragma unroll
    for (int mf = 0; mf < 4; ++mf) {
      const int rb = by * 128 + wr + mf * 16 + l4 * 4;
      if constexpr (EPI == 0) {
#pragma unroll
        for (int nf = 0; nf < 4; ++nf) {
          const int col = nb * 128 + wc + nf * 16 + l15;
          const float bv = bias[(size_t)ge * NLD + col];
#pragma unroll
          for (int j = 0; j < 4; ++j) {
            const int r = rb + j;
            if (r < cnt) {
              const float v = acc[mf][nf][j] + bv;
              const float gl = 0.5f * v * (1.f + erff(v * 0.70710678118654752f));
              Hout[(size_t)(off + r) * NLD + col] = f2bf(gl);
            }
          }
        }
      } else {
#pragma unroll
        for (int j = 0; j < 4; ++j) {
          const int r = rb + j;
          if (r < cnt) {
            const int slot = off + r;
            const float sw = slot_w[slot];
            const int tok = slot_tok[slot];
#pragma unroll
            for (int nf = 0; nf < 4; ++nf) {
              const int col = nb * 128 + wc + nf * 16 + l15;
              const float v = acc[mf][nf][j] + bias[(size_t)ge * NLD + col];
              atomicAdd(&Yout[(size_t)tok * DDIM + col], sw * v);
            }
          }
        }
      }
    }
    // next by-iteration's first CVTW targets buf0, protected by the last
    // steps' barrier + program order (see skew argument) — no extra barrier.
  }
}

// ---------------------------------------------------------------------------
// Workspace layout (bytes):
//   0      counts[32]      256    offsets[32]    512   cursor[32]
//   1024   pair_e[8192]    33792  pair_w[8192]
//   66560  slot_tok[8192]  99328  slot_w[8192]
//   132096 xb[1024][768] bf16 (1.57 MB)
//   12715008 H[8192][3072] bf16 (50.3 MB)     total ~63 MB (ws ~1.2 GB)
// ---------------------------------------------------------------------------
extern "C" void kernel_launch(void* const* d_in, const int* in_sizes, int n_in,
                              void* d_out, int out_size, void* d_ws, size_t ws_size,
                              hipStream_t stream)
{
  const float* x  = (const float*)d_in[0];
  const float* Wg = (const float*)d_in[1];
  const float* bg = (const float*)d_in[2];
  const float* We = (const float*)d_in[3];
  const float* be = (const float*)d_in[4];
  const float* W1 = (const float*)d_in[5];
  const float* b1 = (const float*)d_in[6];
  const float* W2 = (const float*)d_in[7];
  const float* b2 = (const float*)d_in[8];
  float* y = (float*)d_out;

  char* ws = (char*)d_ws;
  int*   counts   = (int*)(ws + 0);
  int*   offsets  = (int*)(ws + 256);
  int*   cursor   = (int*)(ws + 512);
  int*   pair_e   = (int*)(ws + 1024);
  float* pair_w   = (float*)(ws + 33792);
  int*   slot_tok = (int*)(ws + 66560);
  float* slot_w   = (float*)(ws + 99328);
  unsigned short* xb = (unsigned short*)(ws + 132096);
  unsigned short* H  = (unsigned short*)(ws + 12715008);

  init_kernel<<<1, 256, 0, stream>>>((int*)ws);
  zero_y<<<NTOK * DDIM / 1024, 256, 0, stream>>>(y);
  x2bf<<<NTOK * DDIM / 4096, 256, 0, stream>>>(x, xb);
  gating_kernel<<<NTOK, 256, 0, stream>>>(x, Wg, bg, We, be, counts, pair_e, pair_w);
  scan_kernel<<<1, 64, 0, stream>>>(counts, offsets);
  scatter_kernel<<<NPAIR / 256, 256, 0, stream>>>(pair_e, pair_w, offsets, cursor,
                                                  slot_tok, slot_w);

  // FC1: direct from W1 fp32; A gathered from xb via slot_tok.
  moe_gemm_rs<DDIM, MDIM, 0, 1><<<dim3(BYSPAN, MDIM / 128, NEXP), 256, 0, stream>>>(
      xb, W1, b1, counts, offsets, nullptr, slot_tok, H, nullptr);
  // FC2: from H, W2 fp32 direct; fused scaled-atomic epilogue into y.
  moe_gemm_rs<MDIM, DDIM, 1, 0><<<dim3(BYSPAN, DDIM / 128, NEXP), 256, 0, stream>>>(
      H, W2, b2, counts, offsets, slot_w, slot_tok, nullptr, y);
}